// Round 1
// baseline (121.815 us; speedup 1.0000x reference)
//
#include <hip/hip_runtime.h>

// QuinticHermiteSpline: 2^24 fp32 queries, 1024 uniform knots in [0,1].
// Strategy: per-block precompute of per-interval Horner coefficients into LDS
// (2 x float4 per interval), then a grid-stride float4 streaming loop:
//   idx = clamp((int)(x*1023), 0, 1022)   [knots are linspace(0,1,1024)]
//   t   = (x - x_l) * inv_h               [x_l, inv_h from table -> matches ref]
//   val = ((((c5*t+c4)*t+c3)*t+c2)*t+c1)*t+c0
// Memory-bound: 128 MB HBM traffic -> ~20 us floor at 6.3 TB/s.

#define N_KNOTS 1024
#define N_INT   1023

__device__ __forceinline__ float eval_one(float xq,
                                          const float4* __restrict__ cA,
                                          const float4* __restrict__ cB) {
    float s = xq * 1023.0f;
    int idx = (int)s;
    idx = min(max(idx, 0), N_INT - 1);
    float4 a = cA[idx];            // {c5, c4, c3, c2}
    float4 b = cB[idx];            // {c1, c0, x_l, inv_h}
    float t = (xq - b.z) * b.w;
    float v = fmaf(a.x, t, a.y);
    v = fmaf(v, t, a.z);
    v = fmaf(v, t, a.w);
    v = fmaf(v, t, b.x);
    v = fmaf(v, t, b.y);
    return v;
}

__global__ __launch_bounds__(256) void quintic_spline_kernel(
    const float* __restrict__ x_new,
    const float* __restrict__ knots,
    const float* __restrict__ fv,      // [3, 1024]: y, dy, ddy
    float* __restrict__ out,
    int n4)                            // number of float4 groups
{
    __shared__ float4 cA[N_INT];       // {c5, c4, c3, c2=h2*ddyl}
    __shared__ float4 cB[N_INT];       // {c1=h*dyl, c0=yl, x_l, inv_h}

    const float* __restrict__ y   = fv;
    const float* __restrict__ dy  = fv + N_KNOTS;
    const float* __restrict__ ddy = fv + 2 * N_KNOTS;

    // Per-block coefficient precompute: 1023 intervals, 256 threads -> 4 each.
    for (int i = threadIdx.x; i < N_INT; i += 256) {
        float xl   = knots[i];
        float xr   = knots[i + 1];
        float h    = xr - xl;
        float yl   = y[i],   yr   = y[i + 1];
        float dyl  = dy[i],  dyr  = dy[i + 1];
        float ddyl = ddy[i], ddyr = ddy[i + 1];
        float dY = yr - yl;
        float h2 = 0.5f * h * h;
        float c5 =   6.0f * dY - 3.0f * h * (dyl + dyr)          + h2 * (ddyr - ddyl);
        float c4 = -15.0f * dY + h * (8.0f * dyl + 7.0f * dyr)   - h2 * (2.0f * ddyr - 3.0f * ddyl);
        float c3 =  10.0f * dY - 2.0f * h * (3.0f * dyl + 2.0f * dyr) + h2 * (ddyr - 3.0f * ddyl);
        cA[i] = make_float4(c5, c4, c3, h2 * ddyl);
        cB[i] = make_float4(h * dyl, yl, xl, 1.0f / h);
    }
    __syncthreads();

    const float4* __restrict__ x4 = (const float4*)x_new;
    float4* __restrict__ o4 = (float4*)out;

    int stride = gridDim.x * blockDim.x;
    for (int i = blockIdx.x * blockDim.x + threadIdx.x; i < n4; i += stride) {
        float4 xv = x4[i];
        float4 r;
        r.x = eval_one(xv.x, cA, cB);
        r.y = eval_one(xv.y, cA, cB);
        r.z = eval_one(xv.z, cA, cB);
        r.w = eval_one(xv.w, cA, cB);
        o4[i] = r;
    }
}

extern "C" void kernel_launch(void* const* d_in, const int* in_sizes, int n_in,
                              void* d_out, int out_size, void* d_ws, size_t ws_size,
                              hipStream_t stream) {
    const float* x_new = (const float*)d_in[0];
    const float* knots = (const float*)d_in[1];
    const float* fv    = (const float*)d_in[2];
    float* out = (float*)d_out;

    int n = in_sizes[0];          // 16,777,216 (divisible by 4)
    int n4 = n >> 2;              // 4,194,304 float4 groups

    // 2048 blocks x 256 threads; LDS 32.7 KB -> 4 blocks/CU resident,
    // grid-stride loop gives each thread 8 float4 iterations.
    dim3 grid(2048), block(256);
    hipLaunchKernelGGL(quintic_spline_kernel, grid, block, 0, stream,
                       x_new, knots, fv, out, n4);
}